// Round 2
// baseline (113.714 us; speedup 1.0000x reference)
//
#include <hip/hip_runtime.h>

#define NFILT 80
#define NBINS 257          // 512/2 + 1
#define NPTS  (NFILT + 2)  // 82 binpoints
#define NTRI  (NFILT - 1)  // 79 triangular rows (row 79 of fbank is zeros)
#define ROWS  64           // rows per block = lanes per wave
#define BLOCK 256          // 4 waves
#define FPW   (NFILT / 4)  // filters per wave = 20

// Kernel 1: sort binpoints, build per-filter descriptors into ws.
// desc[f*8 + {0..6}] = { bj, bj2, inv_d_rise, inv_d_fall, lj, lj1, lj2 }
__global__ void build_desc_kernel(const float* __restrict__ bp,
                                  float* __restrict__ desc) {
    __shared__ float b[NPTS];
    int tid = threadIdx.x;
    if (tid == 0) {
        float tmp[NPTS];
        for (int i = 0; i < NPTS; ++i) tmp[i] = bp[i];
        for (int i = 1; i < NPTS; ++i) {           // insertion sort, 82 elems
            float v = tmp[i];
            int j = i - 1;
            while (j >= 0 && tmp[j] > v) { tmp[j + 1] = tmp[j]; --j; }
            tmp[j + 1] = v;
        }
        for (int i = 0; i < NPTS; ++i) b[i] = tmp[i];
    }
    __syncthreads();
    if (tid < NTRI) {
        float bj  = b[tid];
        float bj1 = b[tid + 1];
        float bj2 = b[tid + 2];
        float dr = (bj1 - bj) * (bj1 - bj);
        float df = (bj2 - bj1) * (bj2 - bj1);
        float* d = desc + tid * 8;
        d[0] = bj;
        d[1] = bj2;
        d[2] = (dr == 0.0f) ? 1.0f : 1.0f / dr;
        d[3] = (df == 0.0f) ? 1.0f : 1.0f / df;
        d[4] = floorf(bj);
        d[5] = floorf(bj1);
        d[6] = floorf(bj2);
        d[7] = 0.0f;
    }
}

// Kernel 2: 64 rows per block staged in LDS. Each wave handles 20 filters;
// all 64 lanes of a wave process the SAME filter across 64 rows, so the
// gather-loop bounds and weights are wave-uniform (scalar loop, no
// divergence). LDS read bank = (lane*257 + k) % 32 = (lane+k) % 32 ->
// conflict-free (2-way aliasing lane vs lane+32, which is free).
__global__ __launch_bounds__(BLOCK, 2) void filter_apply_kernel(
        const float* __restrict__ x, const float* __restrict__ desc,
        float* __restrict__ out, int nrows) {
    __shared__ float sx[ROWS * NBINS];   // 65792 B
    __shared__ float sd[NTRI * 8];       // 2528 B

    const int tid  = threadIdx.x;
    const int row0 = blockIdx.x * ROWS;
    const int rows = min(ROWS, nrows - row0);
    if (rows <= 0) return;

    for (int i = tid; i < NTRI * 8; i += BLOCK) sd[i] = desc[i];

    if (rows == ROWS) {
        // vectorized staging: 64*257/4 = 4112 float4s, coalesced
        const float4* xb4 = reinterpret_cast<const float4*>(x + (size_t)row0 * NBINS);
        float4* sx4 = reinterpret_cast<float4*>(sx);
        for (int i = tid; i < (ROWS * NBINS) / 4; i += BLOCK) sx4[i] = xb4[i];
    } else {
        const float* xb = x + (size_t)row0 * NBINS;
        for (int i = tid; i < rows * NBINS; i += BLOCK) sx[i] = xb[i];
    }
    __syncthreads();

    const int lane = tid & 63;
    const int wv   = tid >> 6;          // 0..3
    if (lane >= rows) return;           // only in the (non-occurring) tail block

    const float* xr = sx + lane * NBINS;
    float* orow = out + (size_t)(row0 + lane) * NFILT;

    for (int f = wv * FPW; f < (wv + 1) * FPW; ++f) {
        float val;
        if (f == 0) {
            val = xr[0];                 // filtered[:,:,0] = x[:,:,0]
        } else if (f == NFILT - 1) {
            val = 0.0f;                  // fbank row 79 is all zeros
        } else {
            const float* d = sd + f * 8;
            // force wave-uniform loop bounds into SGPRs -> scalar loop
            const int lj  = __builtin_amdgcn_readfirstlane((int)d[4]);
            const int lj1 = __builtin_amdgcn_readfirstlane((int)d[5]);
            const int lj2 = __builtin_amdgcn_readfirstlane((int)d[6]);
            const float bj   = d[0];
            const float bj2  = d[1];
            const float invr = d[2];
            const float invf = d[3];
            float acc = 0.0f;
            for (int k = lj; k < lj1; ++k)
                acc += xr[k] * (((float)k - bj) * invr);
            for (int k = lj1; k < lj2; ++k)
                acc += xr[k] * ((bj2 - (float)k) * invf);
            val = acc;
        }
        orow[f] = val;
    }
}

extern "C" void kernel_launch(void* const* d_in, const int* in_sizes, int n_in,
                              void* d_out, int out_size, void* d_ws, size_t ws_size,
                              hipStream_t stream) {
    const float* x  = (const float*)d_in[0];
    const float* bp = (const float*)d_in[1];
    float* out  = (float*)d_out;
    float* desc = (float*)d_ws;  // needs 79*8*4 = 2528 bytes

    const int nrows = in_sizes[0] / NBINS;  // 32*4096 = 131072

    build_desc_kernel<<<1, 128, 0, stream>>>(bp, desc);

    const int grid = (nrows + ROWS - 1) / ROWS;
    filter_apply_kernel<<<grid, BLOCK, 0, stream>>>(x, desc, out, nrows);
}

// Round 3
// 103.628 us; speedup vs baseline: 1.0973x; 1.0973x over previous
//
#include <hip/hip_runtime.h>

#define NFILT 80
#define NBINS 257          // 512/2 + 1
#define NPTS  (NFILT + 2)  // 82 binpoints
#define NTRI  (NFILT - 1)  // 79 triangular rows (row 79 of fbank is zeros)
#define ROWS  64           // rows per block = lanes per wave
#define BLOCK 1024         // 16 waves
#define NWAVES (BLOCK / 64)
#define FPW   (NFILT / NWAVES)  // filters per wave = 5

// Kernel 1: sort binpoints, build per-filter descriptors into ws.
// desc[f*8 + {0..6}] = { bj, bj2, inv_d_rise, inv_d_fall, lj, lj1, lj2 }
__global__ void build_desc_kernel(const float* __restrict__ bp,
                                  float* __restrict__ desc) {
    __shared__ float b[NPTS];
    int tid = threadIdx.x;
    if (tid == 0) {
        float tmp[NPTS];
        for (int i = 0; i < NPTS; ++i) tmp[i] = bp[i];
        for (int i = 1; i < NPTS; ++i) {           // insertion sort, 82 elems
            float v = tmp[i];
            int j = i - 1;
            while (j >= 0 && tmp[j] > v) { tmp[j + 1] = tmp[j]; --j; }
            tmp[j + 1] = v;
        }
        for (int i = 0; i < NPTS; ++i) b[i] = tmp[i];
    }
    __syncthreads();
    if (tid < NTRI) {
        float bj  = b[tid];
        float bj1 = b[tid + 1];
        float bj2 = b[tid + 2];
        float dr = (bj1 - bj) * (bj1 - bj);
        float df = (bj2 - bj1) * (bj2 - bj1);
        float* d = desc + tid * 8;
        d[0] = bj;
        d[1] = bj2;
        d[2] = (dr == 0.0f) ? 1.0f : 1.0f / dr;
        d[3] = (df == 0.0f) ? 1.0f : 1.0f / df;
        d[4] = floorf(bj);
        d[5] = floorf(bj1);
        d[6] = floorf(bj2);
        d[7] = 0.0f;
    }
}

// Kernel 2: 64 rows per block staged in LDS; 16 waves, 5 filters per wave.
// All 64 lanes of a wave process the SAME filter across 64 rows, so loop
// bounds are wave-uniform (scalar loop). LDS read bank = (lane+k)%32 ->
// conflict-free. LDS 68.6KB -> 2 blocks/CU -> 32 waves/CU (100% occ).
__global__ __launch_bounds__(BLOCK, 8) void filter_apply_kernel(
        const float* __restrict__ x, const float* __restrict__ desc,
        float* __restrict__ out, int nrows) {
    __shared__ float sx[ROWS * NBINS];   // 65792 B
    __shared__ float sd[NTRI * 8];       // 2528 B

    const int tid  = threadIdx.x;
    const int row0 = blockIdx.x * ROWS;
    const int rows = min(ROWS, nrows - row0);
    if (rows <= 0) return;

    if (tid < NTRI * 8) sd[tid] = desc[tid];

    if (rows == ROWS) {
        // 64*257/4 = 4112 float4 loads, coalesced, ~4 per thread
        const float4* xb4 = reinterpret_cast<const float4*>(x + (size_t)row0 * NBINS);
        float4* sx4 = reinterpret_cast<float4*>(sx);
        for (int i = tid; i < (ROWS * NBINS) / 4; i += BLOCK) sx4[i] = xb4[i];
    } else {
        const float* xb = x + (size_t)row0 * NBINS;
        for (int i = tid; i < rows * NBINS; i += BLOCK) sx[i] = xb[i];
    }
    __syncthreads();

    const int lane = tid & 63;
    const int wv   = tid >> 6;          // 0..15
    if (lane >= rows) return;           // tail never occurs (131072 % 64 == 0)

    const float* xr = sx + lane * NBINS;
    float* orow = out + (size_t)(row0 + lane) * NFILT;

    for (int f = wv * FPW; f < (wv + 1) * FPW; ++f) {
        float val;
        if (f == 0) {
            val = xr[0];                 // filtered[:,:,0] = x[:,:,0]
        } else if (f == NFILT - 1) {
            val = 0.0f;                  // fbank row 79 is all zeros
        } else {
            const float* d = sd + f * 8;
            // wave-uniform bounds -> SGPRs -> scalar loop control
            const int lj  = __builtin_amdgcn_readfirstlane((int)d[4]);
            const int lj1 = __builtin_amdgcn_readfirstlane((int)d[5]);
            const int lj2 = __builtin_amdgcn_readfirstlane((int)d[6]);
            const float bj   = d[0];
            const float bj2  = d[1];
            const float invr = d[2];
            const float invf = d[3];
            float acc = 0.0f;
            if (lj < lj2) {
                // fused rise+fall loop, load-ahead by 1 iteration
                float xv = xr[lj];
                int k = lj;
                for (; k < lj2 - 1; ++k) {
                    float xn = xr[k + 1];   // in flight during the FMA below
                    float w = (k < lj1) ? (((float)k - bj) * invr)
                                        : ((bj2 - (float)k) * invf);
                    acc += xv * w;
                    xv = xn;
                }
                float w = (k < lj1) ? (((float)k - bj) * invr)
                                    : ((bj2 - (float)k) * invf);
                acc += xv * w;
            }
            val = acc;
        }
        orow[f] = val;
    }
}

extern "C" void kernel_launch(void* const* d_in, const int* in_sizes, int n_in,
                              void* d_out, int out_size, void* d_ws, size_t ws_size,
                              hipStream_t stream) {
    const float* x  = (const float*)d_in[0];
    const float* bp = (const float*)d_in[1];
    float* out  = (float*)d_out;
    float* desc = (float*)d_ws;  // needs 79*8*4 = 2528 bytes

    const int nrows = in_sizes[0] / NBINS;  // 32*4096 = 131072

    build_desc_kernel<<<1, 128, 0, stream>>>(bp, desc);

    const int grid = (nrows + ROWS - 1) / ROWS;
    filter_apply_kernel<<<grid, BLOCK, 0, stream>>>(x, desc, out, nrows);
}

// Round 4
// 70.467 us; speedup vs baseline: 1.6137x; 1.4706x over previous
//
#include <hip/hip_runtime.h>

#define NFILT 80
#define NBINS 257            // 512/2 + 1
#define NPTS  82             // binpoints
#define NTRI  79             // triangular rows (fbank row 79 is zeros)
#define ROWS  64             // rows per tile = lanes per wave
#define BLOCK 1024           // 16 waves
#define NWAVES 16
#define FPW   5              // filters per wave
#define GRID  256            // 1 block per CU (LDS-limited)
#define OPAD  81             // sout row stride (81*4B -> stride 17 banks, conflict-free)
#define TFLOAT (ROWS * NBINS)   // 16448 floats per tile (65792 B)
#define TVEC   (TFLOAT / 4)     // 4112 float4 chunks

// Async DMA of one 16B chunk: global -> LDS (global_load_lds_dwordx4).
// LDS dest must be linear in lane order (wave-uniform base + lane*16) -- our
// i = tid + j*BLOCK indexing satisfies this exactly.
__device__ __forceinline__ void stage_tile(const float* __restrict__ g,
                                           float* l, int tid) {
#pragma unroll
    for (int j = 0; j < 4; ++j) {
        const int i = (tid + j * BLOCK) * 4;
        __builtin_amdgcn_global_load_lds(
            (const __attribute__((address_space(1))) void*)(g + i),
            (__attribute__((address_space(3))) void*)(l + i), 16, 0, 0);
    }
    if (tid < (TVEC - 4 * BLOCK)) {   // tail: 4112 - 4096 = 16 chunks
        const int i = (tid + 4 * BLOCK) * 4;
        __builtin_amdgcn_global_load_lds(
            (const __attribute__((address_space(1))) void*)(g + i),
            (__attribute__((address_space(3))) void*)(l + i), 16, 0, 0);
    }
}

// Single fused kernel: grid-stride over row-tiles with double-buffered async
// staging. Each wave handles 5 filters for all 64 rows of the tile
// (wave-uniform gather bounds -> scalar loop control, no divergence).
// x-tile LDS reads: bank = (257*lane + k) % 32 = (lane+k) % 32 -> conflict-free.
__global__ __launch_bounds__(BLOCK, 4) void filter_apply_kernel(
        const float* __restrict__ x, const float* __restrict__ bp,
        float* __restrict__ out, int nrows) {
    __shared__ __align__(16) float sx[2][TFLOAT];  // 131584 B double buffer
    __shared__ float sout[ROWS * OPAD];            // 20736 B out-staging
    __shared__ float sd[NTRI * 8];                 // 2528 B descriptors
    __shared__ float sb[NPTS];                     // 328 B sorted binpoints
    // total ~155 KB < 160 KB -> 1 block/CU

    const int tid  = threadIdx.x;
    const int lane = tid & 63;
    const int wv   = tid >> 6;

    const int tiles = nrows / ROWS;                   // 2048
    const int tpb   = (tiles + GRID - 1) / GRID;      // 8 (chunked for locality)
    const int t0    = blockIdx.x * tpb;
    const int t1    = min(t0 + tpb, tiles);
    if (t0 >= t1) return;

    // kick off DMA for the first tile immediately
    stage_tile(x + (size_t)t0 * TFLOAT, sx[0], tid);

    // descriptor build hides under the DMA latency
    if (tid == 0) {
        float tmp[NPTS];
        for (int i = 0; i < NPTS; ++i) tmp[i] = bp[i];
        for (int i = 1; i < NPTS; ++i) {              // insertion sort (input
            float v = tmp[i];                         //  presorted -> linear)
            int j = i - 1;
            while (j >= 0 && tmp[j] > v) { tmp[j + 1] = tmp[j]; --j; }
            tmp[j + 1] = v;
        }
        for (int i = 0; i < NPTS; ++i) sb[i] = tmp[i];
    }
    __syncthreads();
    if (tid < NTRI) {
        float bj  = sb[tid];
        float bj1 = sb[tid + 1];
        float bj2 = sb[tid + 2];
        float dr = (bj1 - bj) * (bj1 - bj);
        float df = (bj2 - bj1) * (bj2 - bj1);
        float* d = sd + tid * 8;
        d[0] = bj;
        d[1] = bj2;
        d[2] = (dr == 0.0f) ? 1.0f : 1.0f / dr;
        d[3] = (df == 0.0f) ? 1.0f : 1.0f / df;
        d[4] = floorf(bj);
        d[5] = floorf(bj1);
        d[6] = floorf(bj2);
        d[7] = 0.0f;
    }
    asm volatile("s_waitcnt vmcnt(0)" ::: "memory");  // first tile landed
    __syncthreads();

    for (int t = t0; t < t1; ++t) {
        const int cur = (t - t0) & 1;
        if (t + 1 < t1)                                // prefetch next tile:
            stage_tile(x + (size_t)(t + 1) * TFLOAT,   // DMA flies during the
                       sx[cur ^ 1], tid);              // compute phase below

        const float* xr = sx[cur] + lane * NBINS;
        float* so = sout + lane * OPAD;
#pragma unroll
        for (int f = wv * FPW; f < wv * FPW + FPW; ++f) {
            float val;
            if (f == 0) {
                val = xr[0];                 // filtered[:,:,0] = x[:,:,0]
            } else if (f == NFILT - 1) {
                val = 0.0f;                  // fbank row 79 is all zeros
            } else {
                const float* d = sd + f * 8;
                const int lj  = __builtin_amdgcn_readfirstlane((int)d[4]);
                const int lj1 = __builtin_amdgcn_readfirstlane((int)d[5]);
                const int lj2 = __builtin_amdgcn_readfirstlane((int)d[6]);
                const float bj   = d[0];
                const float b2   = d[1];
                const float invr = d[2];
                const float invf = d[3];
                float acc = 0.0f;
                if (lj < lj2) {
                    float xv = xr[lj];
                    int k = lj;
                    for (; k < lj2 - 1; ++k) {
                        float xn = xr[k + 1];          // load-ahead
                        float w = (k < lj1) ? (((float)k - bj) * invr)
                                            : ((b2 - (float)k) * invf);
                        acc += xv * w;
                        xv = xn;
                    }
                    float w = (k < lj1) ? (((float)k - bj) * invr)
                                        : ((b2 - (float)k) * invf);
                    acc += xv * w;
                }
                val = acc;
            }
            so[f] = val;
        }
        __syncthreads();   // sout complete (barrier also drains t+1 DMA)

        // coalesced contiguous store of the 64x80 out-tile
        float* ob = out + (size_t)t * (ROWS * NFILT);
#pragma unroll
        for (int j = 0; j < (ROWS * NFILT) / BLOCK; ++j) {  // 5 dwords/thread
            int i = tid + j * BLOCK;
            int r = i / NFILT;                               // magic-mul div
            ob[i] = sout[r * OPAD + (i - r * NFILT)];
        }
        __syncthreads();   // sout reusable; sx[cur^1] ready for next iter
    }
}

extern "C" void kernel_launch(void* const* d_in, const int* in_sizes, int n_in,
                              void* d_out, int out_size, void* d_ws, size_t ws_size,
                              hipStream_t stream) {
    const float* x  = (const float*)d_in[0];
    const float* bp = (const float*)d_in[1];
    float* out = (float*)d_out;

    const int nrows = in_sizes[0] / NBINS;  // 32*4096 = 131072

    filter_apply_kernel<<<GRID, BLOCK, 0, stream>>>(x, bp, out, nrows);
}